// Round 14
// baseline (155.454 us; speedup 1.0000x reference)
//
#include <hip/hip_runtime.h>
#include <hip/hip_bf16.h>

typedef __attribute__((ext_vector_type(8))) short bf16x8;
typedef __attribute__((ext_vector_type(4))) float f32x4;

// ---- ws layout (bytes): 312 B-fragments of 1KB, then embgate f32 ----
#define FRG_G1 0                 // 72 frags: [py*2+dy 0..5][nt=px*2+ch 0..5][ks 0..1]
#define FRG_G2 (72*1024)         // 40:  nt<8,  ks<5  (conv2 zero-expanded, K=160, N=128)
#define FRG_G3 (112*1024)        // 16:  nt<4,  ks<4  (conv3 dense, K=128, N=64)
#define FRG_G4 (128*1024)        // 8:   nt<4,  ks<2  (fc, K=64, N=64)
#define FRG_GX (136*1024)        // 48:  nt<24, ks<2  (gates-x obs part, K=64, N=384)
#define FRG_GH (184*1024)        // 96:  nt<24, ks<4  (gates-h, K=128, N=384)
#define FRG_HD (280*1024)        // 32:  nt<8,  ks<4  (heads, K=128, N=128)
#define OFF_EMB (312*1024)       // 7*384 f32 = bih + aemb[a] @ Wx_act

#define SWZ(r)  (((r)&7)<<4)

__device__ __forceinline__ float fast_sigmoid(float x) {
    return 1.0f / (1.0f + __expf(-x));
}
__device__ __forceinline__ float fast_tanh(float x) {
    float cx = fminf(fmaxf(x, -15.0f), 15.0f);
    float e = __expf(2.0f * cx);
    return (e - 1.0f) / (e + 1.0f);
}
__device__ __forceinline__ unsigned short f2bf(float f) {
    __hip_bfloat16 h = __float2bfloat16(f);
    return *reinterpret_cast<unsigned short*>(&h);
}
__device__ __forceinline__ float bf2f(unsigned short h) {
    return __uint_as_float(((unsigned)h) << 16);
}
__device__ __forceinline__ unsigned packbf(float a, float b) {
    __hip_bfloat162 h = __float22bfloat162_rn(make_float2(a, b));
    return *reinterpret_cast<unsigned*>(&h);
}
__device__ __forceinline__ float dpp_pairswap(float x) {
    return __int_as_float(__builtin_amdgcn_mov_dpp(__float_as_int(x), 0xB1, 0xF, 0xF, true));
}

// ---------------------------------------------------------------------------
// prep: unchanged from R9-R13.
// ---------------------------------------------------------------------------
__global__ __launch_bounds__(64, 4)
void prep(const float* __restrict__ c1w, const float* __restrict__ c2w,
          const float* __restrict__ c3w, const float* __restrict__ fcw,
          const float* __restrict__ wih, const float* __restrict__ whh,
          const float* __restrict__ bih,
          const float* __restrict__ a1w, const float* __restrict__ cr1w,
          const float* __restrict__ aemb,
          char* __restrict__ ws)
{
    const int b = blockIdx.x;
    const int l = threadIdx.x;

    if (b >= 312) {   // embgate
        int item = (b - 312) * 64 + l;
        if (item < 7 * 384) {
            int a = item / 384, n = item % 384;
            float acc = bih[n];
#pragma unroll
            for (int j = 0; j < 16; ++j) acc += aemb[a * 16 + j] * wih[n * 80 + 64 + j];
            ((float*)(ws + OFF_EMB))[item] = acc;
        }
        return;
    }

    const int lr = l & 15, kg = (l >> 4) * 8;
    float v[8];
#pragma unroll
    for (int j = 0; j < 8; ++j) v[j] = 0.0f;

    if (b < 72) {                            // G1: conv1 window GEMM
        int pydy = b / 12, r1 = b % 12, nt = r1 / 2, ks = r1 % 2;
        int py = pydy >> 1, dy = pydy & 1;
        int oy = 2 * py + dy;
        int ox = 2 * (nt >> 1) + (lr & 1);
        int c  = (nt & 1) * 8 + (lr >> 1);
#pragma unroll
        for (int j = 0; j < 8; ++j) {
            int k = ks * 32 + kg + j;
            if (k < 63) {
                int idx = 42 * py + k;
                int y = idx / 21, rem = idx % 21, x = rem / 3, ci = rem % 3;
                int ky = y - oy, kx = x - ox;
                if (ky >= 0 && ky < 2 && kx >= 0 && kx < 2)
                    v[j] = c1w[((c * 3 + ci) * 2 + ky) * 2 + kx];
            }
        }
    } else if (b < 112) {                    // G2: conv2 zero-expanded
        int f = b - 72, nt = f / 5, ks = f % 5;
        int n = nt * 16 + lr;
        int c2 = n >> 2, oy = (n >> 1) & 1, ox = n & 1;
#pragma unroll
        for (int j = 0; j < 8; ++j) {
            int k = ks * 32 + kg + j;
            if (k < 144) {
                int c = k / 9, p9 = k % 9, py = p9 / 3, px = p9 % 3;
                int ky = py - oy, kx = px - ox;
                if (ky >= 0 && ky < 2 && kx >= 0 && kx < 2)
                    v[j] = c2w[((c2 * 16 + c) * 2 + ky) * 2 + kx];
            }
        }
    } else if (b < 128) {                    // G3: conv3 dense (K=128)
        int f = b - 112, nt = f / 4, ks = f % 4;
        int n = nt * 16 + lr;
#pragma unroll
        for (int j = 0; j < 8; ++j) v[j] = c3w[n * 128 + ks * 32 + kg + j];
    } else if (b < 136) {                    // G4: fc (K=64)
        int f = b - 128, nt = f / 2, ks = f % 2;
        int n = nt * 16 + lr;
#pragma unroll
        for (int j = 0; j < 8; ++j) v[j] = fcw[n * 64 + ks * 32 + kg + j];
    } else if (b < 184) {                    // GX: gates-x obs part (K=64)
        int f = b - 136, nt = f / 2, ks = f % 2;
        int n = nt * 16 + lr;
#pragma unroll
        for (int j = 0; j < 8; ++j) v[j] = wih[n * 80 + ks * 32 + kg + j];
    } else if (b < 280) {                    // GH: gates-h (K=128)
        int f = b - 184, nt = f / 4, ks = f % 4;
        int n = nt * 16 + lr;
#pragma unroll
        for (int j = 0; j < 8; ++j) v[j] = whh[n * 128 + ks * 32 + kg + j];
    } else {                                 // HD: heads (K=128, N=128)
        int f = b - 280, nt = f / 4, ks = f % 4;
        int n = nt * 16 + lr;
        const float* w = (n < 64) ? (a1w + n * 128) : (cr1w + (n - 64) * 128);
#pragma unroll
        for (int j = 0; j < 8; ++j) v[j] = w[ks * 32 + kg + j];
    }

    unsigned u[4];
#pragma unroll
    for (int p = 0; p < 4; ++p) u[p] = packbf(v[2 * p], v[2 * p + 1]);
    *(uint4*)(ws + b * 1024 + l * 16) = make_uint4(u[0], u[1], u[2], u[3]);
}

// ---------------------------------------------------------------------------
// fused_agent: 64-sample tile, 512 threads = 8 waves, (512,4) => 128-reg
// budget, 2 blocks/CU. R14: POOLED split into LPA0 (64x256, cols 0-127) +
// LPB (64x128, cols 128-159+pad), both 3-bit SWZ (bank-conflict-free like
// LHS) -- replaces the stride-320 SWZP buffer. LDS 67.9KB.
// ---------------------------------------------------------------------------
#define LOBS  0            // 64 x 384B: 3 windows of 64 bf16 (S0-S1)
#define LPA0  24576        // 64 x 256B  pooled cols 0-127   (S1-S3)
#define LPB   40960        // 64 x 128B  pooled cols 128-159 (S1-S3)
#define LHS   49152        // 64 x 256B  old hidden          (S3-S6)
#define LPAI  65536        // 64 ints
#define LFINW 65792        // 512 f32
#define LFINB 67840        // 8 f32
// overlays:
#define LX2   LOBS             // 64 x 256B  (S3ep-S4)
#define LHN   LOBS             // 64 x 256B  new hidden (S6-S7)
#define LX3   LPA0             // 64 x 128B  (S4ep-S5)
#define LX4   (LPA0 + 8192)    // 64 x 128B  (S5ep-S6)
#define LTS   LPA0             // 64 x 256B  (S7ep-S8)

__global__ __launch_bounds__(512, 4)
void fused_agent(const float* __restrict__ obs, const int* __restrict__ pa_g,
                 const float* __restrict__ hidden,
                 const float* __restrict__ c1b, const float* __restrict__ c2b,
                 const float* __restrict__ c3b, const float* __restrict__ fcb,
                 const float* __restrict__ bhh,
                 const float* __restrict__ a1b, const float* __restrict__ cr1b,
                 const float* __restrict__ a2w, const float* __restrict__ a2b,
                 const float* __restrict__ cr2w, const float* __restrict__ cr2b,
                 const char* __restrict__ ws, float* __restrict__ out, int B)
{
    __shared__ __align__(16) char L[67872];
    float* FINW = (float*)(L + LFINW);
    float* FINB = (float*)(L + LFINB);
    int*   PA   = (int*)(L + LPAI);

    const int tid = threadIdx.x;
    const int l = tid & 63, w = tid >> 6;
    const int lr = l & 15, kg = (l >> 4) * 8;
    const size_t rowBase = (size_t)blockIdx.x * 64;
    const float* EMB = (const float*)(ws + OFF_EMB);

    // ---- S0: stage obs as 3 overlapping 64-value windows/row (shift-only),
    //      zero-pad LPB tail, PA, head weights ----
#pragma unroll
    for (int py = 0; py < 3; ++py) {
        for (int idx = tid; idx < 64 * 32; idx += 512) {
            int r = idx >> 5, k2 = idx & 31;
            const float* src = obs + (rowBase + r) * 147 + 42 * py + 2 * k2;
            float v0 = src[0];
            float v1 = (k2 < 31) ? src[1] : 0.0f;   // k=63 is pad
            *(unsigned*)(L + LOBS + r * 384 + ((py * 128 + 4 * k2) ^ SWZ(r))) = packbf(v0, v1);
        }
    }
    {   // zero-pad LPB cols 144..159 (bytes 32..63 of each 128B row)
        int r = tid >> 3, c2 = tid & 7;
        *(unsigned*)(L + LPB + r * 128 + ((32 + 4 * c2) ^ SWZ(r))) = 0u;
    }
    if (tid < 64) PA[tid] = pa_g[rowBase + tid];
    {
        int j = tid >> 6, c = tid & 63;
        FINW[tid] = (j < 7) ? a2w[j * 64 + c] : cr2w[c];
    }
    if (tid < 8) FINB[tid] = (tid < 7) ? a2b[tid] : cr2b[0];
    __syncthreads();

    // ---- S1: conv1 window GEMMs, flat distribution u = w + 8*i (crit path 3) ----
    {
        const int nu = (w < 2) ? 3 : 2;
        for (int i = 0; i < nu; ++i) {
            const int u = w + 8 * i;           // 0..17
            const int combo = u >> 1, ch = u & 1;
            const int py = combo / 3, px = combo % 3;

            f32x4 acc[2][4];                   // [dy][mt] = 32 acc regs
#pragma unroll
            for (int dy = 0; dy < 2; ++dy)
#pragma unroll
                for (int mt = 0; mt < 4; ++mt) acc[dy][mt] = (f32x4)0.0f;

#pragma unroll
            for (int ks = 0; ks < 2; ++ks) {
                bf16x8 A[4];
#pragma unroll
                for (int mt = 0; mt < 4; ++mt) {
                    int row = mt * 16 + lr;
                    A[mt] = *(const bf16x8*)(L + LOBS + row * 384 +
                             ((py * 128 + ks * 64 + kg * 2) ^ SWZ(row)));
                }
#pragma unroll
                for (int dy = 0; dy < 2; ++dy) {
                    bf16x8 Bf = *(const bf16x8*)(ws + FRG_G1 +
                        (((((py * 2 + dy) * 6) + (px * 2 + ch)) * 2 + ks) << 10) + (l << 4));
#pragma unroll
                    for (int mt = 0; mt < 4; ++mt)
                        acc[dy][mt] = __builtin_amdgcn_mfma_f32_16x16x32_bf16(A[mt], Bf, acc[dy][mt], 0, 0, 0);
                }
            }

            int c  = ch * 8 + (lr >> 1);
            int cp = c * 9 + py * 3 + px;      // pooled col 0..143
            float bias = c1b[c];
#pragma unroll
            for (int mt = 0; mt < 4; ++mt)
#pragma unroll
                for (int q = 0; q < 4; ++q) {
                    float m = fmaxf(acc[0][mt][q], acc[1][mt][q]);
                    float o = fmaxf(m, dpp_pairswap(m));
                    if ((l & 1) == 0) {
                        int row = mt * 16 + (l >> 4) * 4 + q;
                        char* p = (cp < 128)
                            ? (L + LPA0 + row * 256 + ((cp * 2) ^ SWZ(row)))
                            : (L + LPB  + row * 128 + (((cp - 128) * 2) ^ SWZ(row)));
                        *(unsigned short*)p = f2bf(fmaxf(o + bias, 0.0f));
                    }
                }
        }
    }
    __syncthreads();

    // ---- S3: stage H (loads issued early) + G2 = POOLED @ W2e (nt = w) ----
    {
        float2 hv[8];
#pragma unroll
        for (int t = 0; t < 8; ++t) {
            int idx = tid + t * 512;
            int r = idx >> 6, c2 = idx & 63;
            hv[t] = *(const float2*)(hidden + (rowBase + r) * 128 + 2 * c2);
        }

        f32x4 acc[4];
#pragma unroll
        for (int mt = 0; mt < 4; ++mt) acc[mt] = (f32x4)0.0f;
#pragma unroll
        for (int ks = 0; ks < 5; ++ks) {
            bf16x8 A[4];
#pragma unroll
            for (int mt = 0; mt < 4; ++mt) {
                int row = mt * 16 + lr;
                A[mt] = (ks < 4)
                    ? *(const bf16x8*)(L + LPA0 + row * 256 + (((ks * 32 + kg) * 2) ^ SWZ(row)))
                    : *(const bf16x8*)(L + LPB  + row * 128 + ((kg * 2) ^ SWZ(row)));
            }
            bf16x8 Bf = *(const bf16x8*)(ws + FRG_G2 + (w * 5 + ks) * 1024 + l * 16);
#pragma unroll
            for (int mt = 0; mt < 4; ++mt)
                acc[mt] = __builtin_amdgcn_mfma_f32_16x16x32_bf16(A[mt], Bf, acc[mt], 0, 0, 0);
        }

#pragma unroll
        for (int t = 0; t < 8; ++t) {
            int idx = tid + t * 512;
            int r = idx >> 6, c2 = idx & 63;
            *(unsigned*)(L + LHS + r * 256 + ((4 * c2) ^ SWZ(r))) = packbf(hv[t].x, hv[t].y);
        }

        int col = w * 16 + lr;
        float bias = c2b[col >> 2];
#pragma unroll
        for (int mt = 0; mt < 4; ++mt)
#pragma unroll
            for (int q = 0; q < 4; ++q) {
                int row = mt * 16 + (l >> 4) * 4 + q;
                *(unsigned short*)(L + LX2 + row * 256 + ((col * 2) ^ SWZ(row))) =
                    f2bf(fmaxf(acc[mt][q] + bias, 0.0f));
            }
    }
    __syncthreads();

    // ---- S4: G3 = X2 @ W3 (N=64: nt=w&3, row half = w>>2) ----
    {
        int nt = w & 3, mh = (w >> 2) * 2;
        f32x4 acc[2];
        acc[0] = (f32x4)0.0f; acc[1] = (f32x4)0.0f;
#pragma unroll
        for (int ks = 0; ks < 4; ++ks) {
            bf16x8 Bf = *(const bf16x8*)(ws + FRG_G3 + (nt * 4 + ks) * 1024 + l * 16);
#pragma unroll
            for (int m2 = 0; m2 < 2; ++m2) {
                int row = (mh + m2) * 16 + lr;
                bf16x8 A = *(const bf16x8*)(L + LX2 + row * 256 + (((ks * 32 + kg) * 2) ^ SWZ(row)));
                acc[m2] = __builtin_amdgcn_mfma_f32_16x16x32_bf16(A, Bf, acc[m2], 0, 0, 0);
            }
        }
        int col = nt * 16 + lr;
        float bias = c3b[col];
#pragma unroll
        for (int m2 = 0; m2 < 2; ++m2)
#pragma unroll
            for (int q = 0; q < 4; ++q) {
                int row = (mh + m2) * 16 + (l >> 4) * 4 + q;
                *(unsigned short*)(L + LX3 + row * 128 + ((col * 2) ^ SWZ(row))) =
                    f2bf(fmaxf(acc[m2][q] + bias, 0.0f));
            }
    }
    __syncthreads();

    // ---- S5: G4 = X3 @ W4 (fc, K=64) -> X4 = obs_enc ----
    {
        int nt = w & 3, mh = (w >> 2) * 2;
        f32x4 acc[2];
        acc[0] = (f32x4)0.0f; acc[1] = (f32x4)0.0f;
#pragma unroll
        for (int ks = 0; ks < 2; ++ks) {
            bf16x8 Bf = *(const bf16x8*)(ws + FRG_G4 + (nt * 2 + ks) * 1024 + l * 16);
#pragma unroll
            for (int m2 = 0; m2 < 2; ++m2) {
                int row = (mh + m2) * 16 + lr;
                bf16x8 A = *(const bf16x8*)(L + LX3 + row * 128 + (((ks * 32 + kg) * 2) ^ SWZ(row)));
                acc[m2] = __builtin_amdgcn_mfma_f32_16x16x32_bf16(A, Bf, acc[m2], 0, 0, 0);
            }
        }
        int col = nt * 16 + lr;
        float bias = fcb[col];
#pragma unroll
        for (int m2 = 0; m2 < 2; ++m2)
#pragma unroll
            for (int q = 0; q < 4; ++q) {
                int row = (mh + m2) * 16 + (l >> 4) * 4 + q;
                *(unsigned short*)(L + LX4 + row * 128 + ((col * 2) ^ SWZ(row))) =
                    f2bf(fmaxf(acc[m2][q] + bias, 0.0f));
            }
    }
    __syncthreads();

    // ---- S6: GRU gates in two mt-halves (acc peak 32); h_new -> LHN + out ----
    {
        const int nc = w * 16 + lr;
        const float bR = bhh[nc], bZ = bhh[128 + nc], bN = bhh[256 + nc];
#pragma unroll
        for (int h = 0; h < 2; ++h) {
            f32x4 aR[2], aZ[2], aNX[2], aNH[2];    // 32 acc regs
#pragma unroll
            for (int m2 = 0; m2 < 2; ++m2) {
                aR[m2] = (f32x4)0.0f; aZ[m2] = (f32x4)0.0f;
                aNX[m2] = (f32x4)0.0f; aNH[m2] = (f32x4)0.0f;
            }
            // gates-x: K=64 from X4
#pragma unroll
            for (int ks = 0; ks < 2; ++ks) {
                bf16x8 A[2];
#pragma unroll
                for (int m2 = 0; m2 < 2; ++m2) {
                    int row = (h * 2 + m2) * 16 + lr;
                    A[m2] = *(const bf16x8*)(L + LX4 + row * 128 + (((ks * 32 + kg) * 2) ^ SWZ(row)));
                }
#pragma unroll
                for (int g = 0; g < 3; ++g) {
                    int nt = w + 8 * g;
                    bf16x8 Bf = *(const bf16x8*)(ws + FRG_GX + (nt * 2 + ks) * 1024 + l * 16);
#pragma unroll
                    for (int m2 = 0; m2 < 2; ++m2) {
                        if (g == 0)      aR[m2]  = __builtin_amdgcn_mfma_f32_16x16x32_bf16(A[m2], Bf, aR[m2], 0, 0, 0);
                        else if (g == 1) aZ[m2]  = __builtin_amdgcn_mfma_f32_16x16x32_bf16(A[m2], Bf, aZ[m2], 0, 0, 0);
                        else             aNX[m2] = __builtin_amdgcn_mfma_f32_16x16x32_bf16(A[m2], Bf, aNX[m2], 0, 0, 0);
                    }
                }
            }
            // gates-h: K=128 from LHS (old H)
#pragma unroll
            for (int ks = 0; ks < 4; ++ks) {
                bf16x8 A[2];
#pragma unroll
                for (int m2 = 0; m2 < 2; ++m2) {
                    int row = (h * 2 + m2) * 16 + lr;
                    A[m2] = *(const bf16x8*)(L + LHS + row * 256 + (((ks * 32 + kg) * 2) ^ SWZ(row)));
                }
#pragma unroll
                for (int g = 0; g < 3; ++g) {
                    int nt = w + 8 * g;
                    bf16x8 Bf = *(const bf16x8*)(ws + FRG_GH + (nt * 4 + ks) * 1024 + l * 16);
#pragma unroll
                    for (int m2 = 0; m2 < 2; ++m2) {
                        if (g == 0)      aR[m2]  = __builtin_amdgcn_mfma_f32_16x16x32_bf16(A[m2], Bf, aR[m2], 0, 0, 0);
                        else if (g == 1) aZ[m2]  = __builtin_amdgcn_mfma_f32_16x16x32_bf16(A[m2], Bf, aZ[m2], 0, 0, 0);
                        else             aNH[m2] = __builtin_amdgcn_mfma_f32_16x16x32_bf16(A[m2], Bf, aNH[m2], 0, 0, 0);
                    }
                }
            }
#pragma unroll
            for (int m2 = 0; m2 < 2; ++m2)
#pragma unroll
                for (int q = 0; q < 4; ++q) {
                    int row = (h * 2 + m2) * 16 + (l >> 4) * 4 + q;
                    int a = PA[row];
                    const float* eg = EMB + a * 384;
                    float R  = aR[m2][q] + bR + eg[nc];
                    float Z  = aZ[m2][q] + bZ + eg[128 + nc];
                    float NX = aNX[m2][q] + eg[256 + nc];
                    float NH = aNH[m2][q] + bN;
                    float rg = fast_sigmoid(R);
                    float zg = fast_sigmoid(Z);
                    float ng = fast_tanh(NX + rg * NH);
                    float hold = bf2f(*(const unsigned short*)(L + LHS + row * 256 + ((nc * 2) ^ SWZ(row))));
                    float hn = (1.0f - zg) * ng + zg * hold;
                    *(unsigned short*)(L + LHN + row * 256 + ((nc * 2) ^ SWZ(row))) = f2bf(hn);
                    out[(size_t)B * 8 + (rowBase + row) * 128 + nc] = hn;
                }
        }
    }
    __syncthreads();

    // ---- S7: heads = h_new @ [a1w | cr1w], tanh -> TS ----
    {
        f32x4 acc[4];
#pragma unroll
        for (int mt = 0; mt < 4; ++mt) acc[mt] = (f32x4)0.0f;
#pragma unroll
        for (int ks = 0; ks < 4; ++ks) {
            bf16x8 A[4];
#pragma unroll
            for (int mt = 0; mt < 4; ++mt) {
                int row = mt * 16 + lr;
                A[mt] = *(const bf16x8*)(L + LHN + row * 256 + (((ks * 32 + kg) * 2) ^ SWZ(row)));
            }
            bf16x8 Bf = *(const bf16x8*)(ws + FRG_HD + (w * 4 + ks) * 1024 + l * 16);
#pragma unroll
            for (int mt = 0; mt < 4; ++mt)
                acc[mt] = __builtin_amdgcn_mfma_f32_16x16x32_bf16(A[mt], Bf, acc[mt], 0, 0, 0);
        }
        int col = w * 16 + lr;
        float hb = (col < 64) ? a1b[col] : cr1b[col - 64];
#pragma unroll
        for (int mt = 0; mt < 4; ++mt)
#pragma unroll
            for (int q = 0; q < 4; ++q) {
                int row = mt * 16 + (l >> 4) * 4 + q;
                *(unsigned short*)(L + LTS + row * 256 + ((col * 2) ^ SWZ(row))) =
                    f2bf(fast_tanh(acc[mt][q] + hb));
            }
    }
    __syncthreads();

    // ---- S8: final projections. thread: sample = tid>>3, j = tid&7 ----
    {
        int sm = tid >> 3, j = tid & 7;
        const float* wrow = FINW + j * 64;
        float acc = FINB[j];
        int cbase = (j == 7) ? 64 : 0;
#pragma unroll
        for (int c = 0; c < 32; ++c) {
            unsigned u = *(const unsigned*)(L + LTS + sm * 256 + (((cbase + 2 * c) * 2) ^ SWZ(sm)));
            float2 wv = *(const float2*)(wrow + 2 * c);
            acc += bf2f((unsigned short)u) * wv.x +
                   bf2f((unsigned short)(u >> 16)) * wv.y;
        }
        if (j < 7) out[(rowBase + sm) * 7 + j] = acc;
        else       out[(size_t)B * 7 + rowBase + sm] = acc;
    }
}

extern "C" void kernel_launch(void* const* d_in, const int* in_sizes, int n_in,
                              void* d_out, int out_size, void* d_ws, size_t ws_size,
                              hipStream_t stream) {
    const float* obs  = (const float*)d_in[0];
    const int*   pa   = (const int*)d_in[1];
    const float* hid  = (const float*)d_in[2];
    const float* c1w  = (const float*)d_in[3];
    const float* c1b  = (const float*)d_in[4];
    const float* c2w  = (const float*)d_in[5];
    const float* c2b  = (const float*)d_in[6];
    const float* c3w  = (const float*)d_in[7];
    const float* c3b  = (const float*)d_in[8];
    const float* fcw  = (const float*)d_in[9];
    const float* fcb  = (const float*)d_in[10];
    const float* aemb = (const float*)d_in[11];
    const float* wih  = (const float*)d_in[12];
    const float* whh  = (const float*)d_in[13];
    const float* bih  = (const float*)d_in[14];
    const float* bhh  = (const float*)d_in[15];
    const float* a1w  = (const float*)d_in[16];
    const float* a1b  = (const float*)d_in[17];
    const float* a2w  = (const float*)d_in[18];
    const float* a2b  = (const float*)d_in[19];
    const float* cr1w = (const float*)d_in[20];
    const float* cr1b = (const float*)d_in[21];
    const float* cr2w = (const float*)d_in[22];
    const float* cr2b = (const float*)d_in[23];

    const int B = in_sizes[1];
    char* ws = (char*)d_ws;

    prep<<<354, 64, 0, stream>>>(c1w, c2w, c3w, fcw, wih, whh, bih, a1w, cr1w, aemb, ws);
    fused_agent<<<B / 64, 512, 0, stream>>>(
        obs, pa, hid, c1b, c2b, c3b, fcb, bhh, a1b, cr1b,
        a2w, a2b, cr2w, cr2b, ws, (float*)d_out, B);
}

// Round 15
// 149.612 us; speedup vs baseline: 1.0390x; 1.0390x over previous
//
#include <hip/hip_runtime.h>
#include <hip/hip_bf16.h>

typedef __attribute__((ext_vector_type(8))) short bf16x8;
typedef __attribute__((ext_vector_type(4))) float f32x4;

// ---- ws layout (bytes): 312 B-fragments of 1KB, then embgate f32 ----
#define FRG_G1 0                 // 72 frags: [py*2+dy 0..5][nt=px*2+ch 0..5][ks 0..1]
#define FRG_G2 (72*1024)         // 40:  nt<8,  ks<5  (conv2 zero-expanded, K=160, N=128)
#define FRG_G3 (112*1024)        // 16:  nt<4,  ks<4  (conv3 dense, K=128, N=64)
#define FRG_G4 (128*1024)        // 8:   nt<4,  ks<2  (fc, K=64, N=64)
#define FRG_GX (136*1024)        // 48:  nt<24, ks<2  (gates-x obs part, K=64, N=384)
#define FRG_GH (184*1024)        // 96:  nt<24, ks<4  (gates-h, K=128, N=384)
#define FRG_HD (280*1024)        // 32:  nt<8,  ks<4  (heads, K=128, N=128)
#define OFF_EMB (312*1024)       // 7*384 f32 = bih + aemb[a] @ Wx_act

#define SWZ(r)  (((r)&7)<<4)
#define SWZP(r) (((((r)&3)^(((r)>>2)&3)))<<4)

__device__ __forceinline__ float fast_sigmoid(float x) {
    return 1.0f / (1.0f + __expf(-x));
}
__device__ __forceinline__ float fast_tanh(float x) {
    float cx = fminf(fmaxf(x, -15.0f), 15.0f);
    float e = __expf(2.0f * cx);
    return (e - 1.0f) / (e + 1.0f);
}
__device__ __forceinline__ unsigned short f2bf(float f) {
    __hip_bfloat16 h = __float2bfloat16(f);
    return *reinterpret_cast<unsigned short*>(&h);
}
__device__ __forceinline__ float bf2f(unsigned short h) {
    return __uint_as_float(((unsigned)h) << 16);
}
__device__ __forceinline__ unsigned packbf(float a, float b) {
    __hip_bfloat162 h = __float22bfloat162_rn(make_float2(a, b));
    return *reinterpret_cast<unsigned*>(&h);
}
__device__ __forceinline__ float dpp_pairswap(float x) {
    return __int_as_float(__builtin_amdgcn_mov_dpp(__float_as_int(x), 0xB1, 0xF, 0xF, true));
}

// ---------------------------------------------------------------------------
// prep: unchanged from R9-R13.
// ---------------------------------------------------------------------------
__global__ __launch_bounds__(64, 4)
void prep(const float* __restrict__ c1w, const float* __restrict__ c2w,
          const float* __restrict__ c3w, const float* __restrict__ fcw,
          const float* __restrict__ wih, const float* __restrict__ whh,
          const float* __restrict__ bih,
          const float* __restrict__ a1w, const float* __restrict__ cr1w,
          const float* __restrict__ aemb,
          char* __restrict__ ws)
{
    const int b = blockIdx.x;
    const int l = threadIdx.x;

    if (b >= 312) {   // embgate
        int item = (b - 312) * 64 + l;
        if (item < 7 * 384) {
            int a = item / 384, n = item % 384;
            float acc = bih[n];
#pragma unroll
            for (int j = 0; j < 16; ++j) acc += aemb[a * 16 + j] * wih[n * 80 + 64 + j];
            ((float*)(ws + OFF_EMB))[item] = acc;
        }
        return;
    }

    const int lr = l & 15, kg = (l >> 4) * 8;
    float v[8];
#pragma unroll
    for (int j = 0; j < 8; ++j) v[j] = 0.0f;

    if (b < 72) {                            // G1: conv1 window GEMM
        int pydy = b / 12, r1 = b % 12, nt = r1 / 2, ks = r1 % 2;
        int py = pydy >> 1, dy = pydy & 1;
        int oy = 2 * py + dy;
        int ox = 2 * (nt >> 1) + (lr & 1);
        int c  = (nt & 1) * 8 + (lr >> 1);
#pragma unroll
        for (int j = 0; j < 8; ++j) {
            int k = ks * 32 + kg + j;
            if (k < 63) {
                int idx = 42 * py + k;
                int y = idx / 21, rem = idx % 21, x = rem / 3, ci = rem % 3;
                int ky = y - oy, kx = x - ox;
                if (ky >= 0 && ky < 2 && kx >= 0 && kx < 2)
                    v[j] = c1w[((c * 3 + ci) * 2 + ky) * 2 + kx];
            }
        }
    } else if (b < 112) {                    // G2: conv2 zero-expanded
        int f = b - 72, nt = f / 5, ks = f % 5;
        int n = nt * 16 + lr;
        int c2 = n >> 2, oy = (n >> 1) & 1, ox = n & 1;
#pragma unroll
        for (int j = 0; j < 8; ++j) {
            int k = ks * 32 + kg + j;
            if (k < 144) {
                int c = k / 9, p9 = k % 9, py = p9 / 3, px = p9 % 3;
                int ky = py - oy, kx = px - ox;
                if (ky >= 0 && ky < 2 && kx >= 0 && kx < 2)
                    v[j] = c2w[((c2 * 16 + c) * 2 + ky) * 2 + kx];
            }
        }
    } else if (b < 128) {                    // G3: conv3 dense (K=128)
        int f = b - 112, nt = f / 4, ks = f % 4;
        int n = nt * 16 + lr;
#pragma unroll
        for (int j = 0; j < 8; ++j) v[j] = c3w[n * 128 + ks * 32 + kg + j];
    } else if (b < 136) {                    // G4: fc (K=64)
        int f = b - 128, nt = f / 2, ks = f % 2;
        int n = nt * 16 + lr;
#pragma unroll
        for (int j = 0; j < 8; ++j) v[j] = fcw[n * 64 + ks * 32 + kg + j];
    } else if (b < 184) {                    // GX: gates-x obs part (K=64)
        int f = b - 136, nt = f / 2, ks = f % 2;
        int n = nt * 16 + lr;
#pragma unroll
        for (int j = 0; j < 8; ++j) v[j] = wih[n * 80 + ks * 32 + kg + j];
    } else if (b < 280) {                    // GH: gates-h (K=128)
        int f = b - 184, nt = f / 4, ks = f % 4;
        int n = nt * 16 + lr;
#pragma unroll
        for (int j = 0; j < 8; ++j) v[j] = whh[n * 128 + ks * 32 + kg + j];
    } else {                                 // HD: heads (K=128, N=128)
        int f = b - 280, nt = f / 4, ks = f % 4;
        int n = nt * 16 + lr;
        const float* w = (n < 64) ? (a1w + n * 128) : (cr1w + (n - 64) * 128);
#pragma unroll
        for (int j = 0; j < 8; ++j) v[j] = w[ks * 32 + kg + j];
    }

    unsigned u[4];
#pragma unroll
    for (int p = 0; p < 4; ++p) u[p] = packbf(v[2 * p], v[2 * p + 1]);
    *(uint4*)(ws + b * 1024 + l * 16) = make_uint4(u[0], u[1], u[2], u[3]);
}

// ---------------------------------------------------------------------------
// fused_agent: R13 (best verified): 64-sample tile, 512 threads = 8 waves,
// (512,4) => 128-reg budget, 2 blocks/CU. S1 flat distribution (crit path 3);
// S0 shift-only staging; h_new to LHN, no intra-S6 barrier. LDS 78.3KB.
// ---------------------------------------------------------------------------
#define LOBS  0            // 64 x 384B: 3 windows of 64 bf16
#define LPOOL 24576        // 64 x 320B  (pooled K=160 bf16, SWZP)
#define LHS   45056        // 64 x 256B  (old hidden, K=128 bf16)
#define LHN   61440        // 64 x 256B  (new hidden, K=128 bf16)
#define LPA   77824        // 64 ints
#define LFINW 78080        // 512 f32
#define LFINB 80128        // 8 f32
// overlays:
#define LX2   LOBS             // 64 x 256B
#define LX3   LPOOL            // 64 x 128B
#define LX4   (LPOOL + 8192)   // 64 x 128B
#define LTS   LOBS             // 64 x 256B

__global__ __launch_bounds__(512, 4)
void fused_agent(const float* __restrict__ obs, const int* __restrict__ pa_g,
                 const float* __restrict__ hidden,
                 const float* __restrict__ c1b, const float* __restrict__ c2b,
                 const float* __restrict__ c3b, const float* __restrict__ fcb,
                 const float* __restrict__ bhh,
                 const float* __restrict__ a1b, const float* __restrict__ cr1b,
                 const float* __restrict__ a2w, const float* __restrict__ a2b,
                 const float* __restrict__ cr2w, const float* __restrict__ cr2b,
                 const char* __restrict__ ws, float* __restrict__ out, int B)
{
    __shared__ __align__(16) char L[80160];
    float* FINW = (float*)(L + LFINW);
    float* FINB = (float*)(L + LFINB);
    int*   PA   = (int*)(L + LPA);

    const int tid = threadIdx.x;
    const int l = tid & 63, w = tid >> 6;
    const int lr = l & 15, kg = (l >> 4) * 8;
    const size_t rowBase = (size_t)blockIdx.x * 64;
    const float* EMB = (const float*)(ws + OFF_EMB);

    // ---- S0: stage obs as 3 overlapping 64-value windows/row (shift-only),
    //      PA, head weights ----
#pragma unroll
    for (int py = 0; py < 3; ++py) {
        for (int idx = tid; idx < 64 * 32; idx += 512) {
            int r = idx >> 5, k2 = idx & 31;
            const float* src = obs + (rowBase + r) * 147 + 42 * py + 2 * k2;
            float v0 = src[0];
            float v1 = (k2 < 31) ? src[1] : 0.0f;   // k=63 is pad
            *(unsigned*)(L + LOBS + r * 384 + ((py * 128 + 4 * k2) ^ SWZ(r))) = packbf(v0, v1);
        }
    }
    {   // zero-pad POOLED cols 144..159
        int r = tid >> 3, c2 = tid & 7;
        *(unsigned*)(L + LPOOL + r * 320 + ((288 + 4 * c2) ^ SWZP(r))) = 0u;
    }
    if (tid < 64) PA[tid] = pa_g[rowBase + tid];
    {
        int j = tid >> 6, c = tid & 63;
        FINW[tid] = (j < 7) ? a2w[j * 64 + c] : cr2w[c];
    }
    if (tid < 8) FINB[tid] = (tid < 7) ? a2b[tid] : cr2b[0];
    __syncthreads();

    // ---- S1: conv1 window GEMMs, flat distribution: u = w + 8*i over 18 units
    //      (waves 0-1: 3 units, waves 2-7: 2 units; crit path 3) ----
    {
        const int nu = (w < 2) ? 3 : 2;
        for (int i = 0; i < nu; ++i) {
            const int u = w + 8 * i;           // 0..17
            const int combo = u >> 1, ch = u & 1;
            const int py = combo / 3, px = combo % 3;

            f32x4 acc[2][4];                   // [dy][mt] = 32 acc regs
#pragma unroll
            for (int dy = 0; dy < 2; ++dy)
#pragma unroll
                for (int mt = 0; mt < 4; ++mt) acc[dy][mt] = (f32x4)0.0f;

#pragma unroll
            for (int ks = 0; ks < 2; ++ks) {
                bf16x8 A[4];
#pragma unroll
                for (int mt = 0; mt < 4; ++mt) {
                    int row = mt * 16 + lr;
                    A[mt] = *(const bf16x8*)(L + LOBS + row * 384 +
                             ((py * 128 + ks * 64 + kg * 2) ^ SWZ(row)));
                }
#pragma unroll
                for (int dy = 0; dy < 2; ++dy) {
                    bf16x8 Bf = *(const bf16x8*)(ws + FRG_G1 +
                        (((((py * 2 + dy) * 6) + (px * 2 + ch)) * 2 + ks) << 10) + (l << 4));
#pragma unroll
                    for (int mt = 0; mt < 4; ++mt)
                        acc[dy][mt] = __builtin_amdgcn_mfma_f32_16x16x32_bf16(A[mt], Bf, acc[dy][mt], 0, 0, 0);
                }
            }

            int c  = ch * 8 + (lr >> 1);
            int cp = c * 9 + py * 3 + px;
            float bias = c1b[c];
#pragma unroll
            for (int mt = 0; mt < 4; ++mt)
#pragma unroll
                for (int q = 0; q < 4; ++q) {
                    float m = fmaxf(acc[0][mt][q], acc[1][mt][q]);
                    float o = fmaxf(m, dpp_pairswap(m));
                    if ((l & 1) == 0) {
                        int row = mt * 16 + (l >> 4) * 4 + q;
                        *(unsigned short*)(L + LPOOL + row * 320 + ((cp * 2) ^ SWZP(row))) =
                            f2bf(fmaxf(o + bias, 0.0f));
                    }
                }
        }
    }
    __syncthreads();

    // ---- S3: stage H (loads issued early) + G2 = POOLED @ W2e (nt = w) ----
    {
        float2 hv[8];
#pragma unroll
        for (int t = 0; t < 8; ++t) {
            int idx = tid + t * 512;
            int r = idx >> 6, c2 = idx & 63;
            hv[t] = *(const float2*)(hidden + (rowBase + r) * 128 + 2 * c2);
        }

        f32x4 acc[4];
#pragma unroll
        for (int mt = 0; mt < 4; ++mt) acc[mt] = (f32x4)0.0f;
#pragma unroll
        for (int ks = 0; ks < 5; ++ks) {
            bf16x8 A[4];
#pragma unroll
            for (int mt = 0; mt < 4; ++mt) {
                int row = mt * 16 + lr;
                A[mt] = *(const bf16x8*)(L + LPOOL + row * 320 + (((ks * 32 + kg) * 2) ^ SWZP(row)));
            }
            bf16x8 Bf = *(const bf16x8*)(ws + FRG_G2 + (w * 5 + ks) * 1024 + l * 16);
#pragma unroll
            for (int mt = 0; mt < 4; ++mt)
                acc[mt] = __builtin_amdgcn_mfma_f32_16x16x32_bf16(A[mt], Bf, acc[mt], 0, 0, 0);
        }

#pragma unroll
        for (int t = 0; t < 8; ++t) {
            int idx = tid + t * 512;
            int r = idx >> 6, c2 = idx & 63;
            *(unsigned*)(L + LHS + r * 256 + ((4 * c2) ^ SWZ(r))) = packbf(hv[t].x, hv[t].y);
        }

        int col = w * 16 + lr;
        float bias = c2b[col >> 2];
#pragma unroll
        for (int mt = 0; mt < 4; ++mt)
#pragma unroll
            for (int q = 0; q < 4; ++q) {
                int row = mt * 16 + (l >> 4) * 4 + q;
                *(unsigned short*)(L + LX2 + row * 256 + ((col * 2) ^ SWZ(row))) =
                    f2bf(fmaxf(acc[mt][q] + bias, 0.0f));
            }
    }
    __syncthreads();

    // ---- S4: G3 = X2 @ W3 (N=64: nt=w&3, row half = w>>2) ----
    {
        int nt = w & 3, mh = (w >> 2) * 2;
        f32x4 acc[2];
        acc[0] = (f32x4)0.0f; acc[1] = (f32x4)0.0f;
#pragma unroll
        for (int ks = 0; ks < 4; ++ks) {
            bf16x8 Bf = *(const bf16x8*)(ws + FRG_G3 + (nt * 4 + ks) * 1024 + l * 16);
#pragma unroll
            for (int m2 = 0; m2 < 2; ++m2) {
                int row = (mh + m2) * 16 + lr;
                bf16x8 A = *(const bf16x8*)(L + LX2 + row * 256 + (((ks * 32 + kg) * 2) ^ SWZ(row)));
                acc[m2] = __builtin_amdgcn_mfma_f32_16x16x32_bf16(A, Bf, acc[m2], 0, 0, 0);
            }
        }
        int col = nt * 16 + lr;
        float bias = c3b[col];
#pragma unroll
        for (int m2 = 0; m2 < 2; ++m2)
#pragma unroll
            for (int q = 0; q < 4; ++q) {
                int row = (mh + m2) * 16 + (l >> 4) * 4 + q;
                *(unsigned short*)(L + LX3 + row * 128 + ((col * 2) ^ SWZ(row))) =
                    f2bf(fmaxf(acc[m2][q] + bias, 0.0f));
            }
    }
    __syncthreads();

    // ---- S5: G4 = X3 @ W4 (fc, K=64) -> X4 = obs_enc ----
    {
        int nt = w & 3, mh = (w >> 2) * 2;
        f32x4 acc[2];
        acc[0] = (f32x4)0.0f; acc[1] = (f32x4)0.0f;
#pragma unroll
        for (int ks = 0; ks < 2; ++ks) {
            bf16x8 Bf = *(const bf16x8*)(ws + FRG_G4 + (nt * 2 + ks) * 1024 + l * 16);
#pragma unroll
            for (int m2 = 0; m2 < 2; ++m2) {
                int row = (mh + m2) * 16 + lr;
                bf16x8 A = *(const bf16x8*)(L + LX3 + row * 128 + (((ks * 32 + kg) * 2) ^ SWZ(row)));
                acc[m2] = __builtin_amdgcn_mfma_f32_16x16x32_bf16(A, Bf, acc[m2], 0, 0, 0);
            }
        }
        int col = nt * 16 + lr;
        float bias = fcb[col];
#pragma unroll
        for (int m2 = 0; m2 < 2; ++m2)
#pragma unroll
            for (int q = 0; q < 4; ++q) {
                int row = (mh + m2) * 16 + (l >> 4) * 4 + q;
                *(unsigned short*)(L + LX4 + row * 128 + ((col * 2) ^ SWZ(row))) =
                    f2bf(fmaxf(acc[m2][q] + bias, 0.0f));
            }
    }
    __syncthreads();

    // ---- S6: GRU gates in two mt-halves (acc peak 32); h_new -> LHN + out.
    //      Old H in LHS is never overwritten: no intra-S6 barrier needed. ----
    {
        const int nc = w * 16 + lr;
        const float bR = bhh[nc], bZ = bhh[128 + nc], bN = bhh[256 + nc];
#pragma unroll
        for (int h = 0; h < 2; ++h) {
            f32x4 aR[2], aZ[2], aNX[2], aNH[2];    // 32 acc regs
#pragma unroll
            for (int m2 = 0; m2 < 2; ++m2) {
                aR[m2] = (f32x4)0.0f; aZ[m2] = (f32x4)0.0f;
                aNX[m2] = (f32x4)0.0f; aNH[m2] = (f32x4)0.0f;
            }
            // gates-x: K=64 from X4
#pragma unroll
            for (int ks = 0; ks < 2; ++ks) {
                bf16x8 A[2];
#pragma unroll
                for (int m2 = 0; m2 < 2; ++m2) {
                    int row = (h * 2 + m2) * 16 + lr;
                    A[m2] = *(const bf16x8*)(L + LX4 + row * 128 + (((ks * 32 + kg) * 2) ^ SWZ(row)));
                }
#pragma unroll
                for (int g = 0; g < 3; ++g) {
                    int nt = w + 8 * g;
                    bf16x8 Bf = *(const bf16x8*)(ws + FRG_GX + (nt * 2 + ks) * 1024 + l * 16);
#pragma unroll
                    for (int m2 = 0; m2 < 2; ++m2) {
                        if (g == 0)      aR[m2]  = __builtin_amdgcn_mfma_f32_16x16x32_bf16(A[m2], Bf, aR[m2], 0, 0, 0);
                        else if (g == 1) aZ[m2]  = __builtin_amdgcn_mfma_f32_16x16x32_bf16(A[m2], Bf, aZ[m2], 0, 0, 0);
                        else             aNX[m2] = __builtin_amdgcn_mfma_f32_16x16x32_bf16(A[m2], Bf, aNX[m2], 0, 0, 0);
                    }
                }
            }
            // gates-h: K=128 from LHS (old H)
#pragma unroll
            for (int ks = 0; ks < 4; ++ks) {
                bf16x8 A[2];
#pragma unroll
                for (int m2 = 0; m2 < 2; ++m2) {
                    int row = (h * 2 + m2) * 16 + lr;
                    A[m2] = *(const bf16x8*)(L + LHS + row * 256 + (((ks * 32 + kg) * 2) ^ SWZ(row)));
                }
#pragma unroll
                for (int g = 0; g < 3; ++g) {
                    int nt = w + 8 * g;
                    bf16x8 Bf = *(const bf16x8*)(ws + FRG_GH + (nt * 4 + ks) * 1024 + l * 16);
#pragma unroll
                    for (int m2 = 0; m2 < 2; ++m2) {
                        if (g == 0)      aR[m2]  = __builtin_amdgcn_mfma_f32_16x16x32_bf16(A[m2], Bf, aR[m2], 0, 0, 0);
                        else if (g == 1) aZ[m2]  = __builtin_amdgcn_mfma_f32_16x16x32_bf16(A[m2], Bf, aZ[m2], 0, 0, 0);
                        else             aNH[m2] = __builtin_amdgcn_mfma_f32_16x16x32_bf16(A[m2], Bf, aNH[m2], 0, 0, 0);
                    }
                }
            }
#pragma unroll
            for (int m2 = 0; m2 < 2; ++m2)
#pragma unroll
                for (int q = 0; q < 4; ++q) {
                    int row = (h * 2 + m2) * 16 + (l >> 4) * 4 + q;
                    int a = PA[row];
                    const float* eg = EMB + a * 384;
                    float R  = aR[m2][q] + bR + eg[nc];
                    float Z  = aZ[m2][q] + bZ + eg[128 + nc];
                    float NX = aNX[m2][q] + eg[256 + nc];
                    float NH = aNH[m2][q] + bN;
                    float rg = fast_sigmoid(R);
                    float zg = fast_sigmoid(Z);
                    float ng = fast_tanh(NX + rg * NH);
                    float hold = bf2f(*(const unsigned short*)(L + LHS + row * 256 + ((nc * 2) ^ SWZ(row))));
                    float hn = (1.0f - zg) * ng + zg * hold;
                    *(unsigned short*)(L + LHN + row * 256 + ((nc * 2) ^ SWZ(row))) = f2bf(hn);
                    out[(size_t)B * 8 + (rowBase + row) * 128 + nc] = hn;
                }
        }
    }
    __syncthreads();

    // ---- S7: heads = h_new @ [a1w | cr1w], tanh -> TS ----
    {
        f32x4 acc[4];
#pragma unroll
        for (int mt = 0; mt < 4; ++mt) acc[mt] = (f32x4)0.0f;
#pragma unroll
        for (int ks = 0; ks < 4; ++ks) {
            bf16x8 A[4];
#pragma unroll
            for (int mt = 0; mt < 4; ++mt) {
                int row = mt * 16 + lr;
                A[mt] = *(const bf16x8*)(L + LHN + row * 256 + (((ks * 32 + kg) * 2) ^ SWZ(row)));
            }
            bf16x8 Bf = *(const bf16x8*)(ws + FRG_HD + (w * 4 + ks) * 1024 + l * 16);
#pragma unroll
            for (int mt = 0; mt < 4; ++mt)
                acc[mt] = __builtin_amdgcn_mfma_f32_16x16x32_bf16(A[mt], Bf, acc[mt], 0, 0, 0);
        }
        int col = w * 16 + lr;
        float hb = (col < 64) ? a1b[col] : cr1b[col - 64];
#pragma unroll
        for (int mt = 0; mt < 4; ++mt)
#pragma unroll
            for (int q = 0; q < 4; ++q) {
                int row = mt * 16 + (l >> 4) * 4 + q;
                *(unsigned short*)(L + LTS + row * 256 + ((col * 2) ^ SWZ(row))) =
                    f2bf(fast_tanh(acc[mt][q] + hb));
            }
    }
    __syncthreads();

    // ---- S8: final projections. thread: sample = tid>>3, j = tid&7 ----
    {
        int sm = tid >> 3, j = tid & 7;
        const float* wrow = FINW + j * 64;
        float acc = FINB[j];
        int cbase = (j == 7) ? 64 : 0;
#pragma unroll
        for (int c = 0; c < 32; ++c) {
            unsigned u = *(const unsigned*)(L + LTS + sm * 256 + (((cbase + 2 * c) * 2) ^ SWZ(sm)));
            float2 wv = *(const float2*)(wrow + 2 * c);
            acc += bf2f((unsigned short)u) * wv.x +
                   bf2f((unsigned short)(u >> 16)) * wv.y;
        }
        if (j < 7) out[(rowBase + sm) * 7 + j] = acc;
        else       out[(size_t)B * 7 + rowBase + sm] = acc;
    }
}

extern "C" void kernel_launch(void* const* d_in, const int* in_sizes, int n_in,
                              void* d_out, int out_size, void* d_ws, size_t ws_size,
                              hipStream_t stream) {
    const float* obs  = (const float*)d_in[0];
    const int*   pa   = (const int*)d_in[1];
    const float* hid  = (const float*)d_in[2];
    const float* c1w  = (const float*)d_in[3];
    const float* c1b  = (const float*)d_in[4];
    const float* c2w  = (const float*)d_in[5];
    const float* c2b  = (const float*)d_in[6];
    const float* c3w  = (const float*)d_in[7];
    const float* c3b  = (const float*)d_in[8];
    const float* fcw  = (const float*)d_in[9];
    const float* fcb  = (const float*)d_in[10];
    const float* aemb = (const float*)d_in[11];
    const float* wih  = (const float*)d_in[12];
    const float* whh  = (const float*)d_in[13];
    const float* bih  = (const float*)d_in[14];
    const float* bhh  = (const float*)d_in[15];
    const float* a1w  = (const float*)d_in[16];
    const float* a1b  = (const float*)d_in[17];
    const float* a2w  = (const float*)d_in[18];
    const float* a2b  = (const float*)d_in[19];
    const float* cr1w = (const float*)d_in[20];
    const float* cr1b = (const float*)d_in[21];
    const float* cr2w = (const float*)d_in[22];
    const float* cr2b = (const float*)d_in[23];

    const int B = in_sizes[1];
    char* ws = (char*)d_ws;

    prep<<<354, 64, 0, stream>>>(c1w, c2w, c3w, fcw, wih, whh, bih, a1w, cr1w, aemb, ws);
    fused_agent<<<B / 64, 512, 0, stream>>>(
        obs, pa, hid, c1b, c2b, c3b, fcb, bhh, a1b, cr1b,
        a2w, a2b, cr2w, cr2b, ws, (float*)d_out, B);
}